// Round 3
// baseline (862.126 us; speedup 1.0000x reference)
//
#include <hip/hip_runtime.h>
#include <hip/hip_bf16.h>
#include <stdint.h>

// Problem constants
#define ROWS 16384      // B*L
#define SEQ  4096
#define CT   16         // chunk length
#define NC   256        // chunks per sequence
#define NBH  32         // B*NUM_HEADS

typedef __attribute__((ext_vector_type(8))) short bf16x8;
typedef __attribute__((ext_vector_type(4))) float f32x4;

__device__ __forceinline__ float bf2f(unsigned short u){
  unsigned int x = ((unsigned int)u) << 16;
  float f; __builtin_memcpy(&f, &x, 4); return f;
}
__device__ __forceinline__ unsigned short f2bf(float f){
  __hip_bfloat16 h = __float2bfloat16(f);
  unsigned short u; __builtin_memcpy(&u, &h, 2); return u;
}

// ---------------- prep kernels ----------------

// x (f32) -> bf16, 8 elems/thread
__global__ __launch_bounds__(256) void k_prep_x(const float* __restrict__ x,
                                                unsigned short* __restrict__ xbf){
  int id = blockIdx.x*256 + threadIdx.x;         // 2,097,152 threads
  const float4* in = (const float4*)x;
  float4 a = in[(size_t)id*2], b = in[(size_t)id*2+1];
  union { unsigned short s[8]; uint4 v; } u;
  u.s[0]=f2bf(a.x); u.s[1]=f2bf(a.y); u.s[2]=f2bf(a.z); u.s[3]=f2bf(a.w);
  u.s[4]=f2bf(b.x); u.s[5]=f2bf(b.y); u.s[6]=f2bf(b.z); u.s[7]=f2bf(b.w);
  ((uint4*)xbf)[id] = u.v;
}

// W_dt_eff^T = (W_sel[:, :32] @ dt_W)^T  -> Wcat rows [0,512)
__global__ __launch_bounds__(256) void k_prep_dteff(const float* __restrict__ Wsel,
                                                    const float* __restrict__ dtW,
                                                    unsigned short* __restrict__ wcat){
  int id = blockIdx.x*256 + threadIdx.x;         // 524288
  int n = id >> 10, kk = id & 1023;
  float acc = 0.f;
  #pragma unroll
  for(int j=0;j<32;j++) acc += Wsel[kk*160 + j] * dtW[j*512 + n];
  wcat[(size_t)n*1024 + kk] = f2bf(acc);
}

// w_bs = mean over W_sel[:,32:96] -> Wcat row 2560
__global__ __launch_bounds__(256) void k_prep_wbs(const float* __restrict__ Wsel,
                                                  unsigned short* __restrict__ wcat){
  int kk = blockIdx.x*256 + threadIdx.x;         // 1024
  float acc = 0.f;
  #pragma unroll
  for(int j=0;j<64;j++) acc += Wsel[kk*160 + 32 + j];
  wcat[(size_t)2560*1024 + kk] = f2bf(acc * (1.0f/64.0f));
}

// src[R][C] f32 -> dst[C][R] bf16 (tiled transpose)
__global__ __launch_bounds__(256) void k_transpose(const float* __restrict__ src,
                                                   unsigned short* __restrict__ dst,
                                                   int R, int C){
  __shared__ float tile[32][33];
  int tx = threadIdx.x & 31, ty = threadIdx.x >> 5;
  int r0 = blockIdx.x*32, c0 = blockIdx.y*32;
  #pragma unroll
  for(int i=0;i<4;i++) tile[ty+i*8][tx] = src[(size_t)(r0+ty+i*8)*C + c0+tx];
  __syncthreads();
  #pragma unroll
  for(int i=0;i<4;i++) dst[(size_t)(c0+ty+i*8)*R + r0+tx] = f2bf(tile[tx][ty+i*8]);
}

// ---------------- GEMM (128x128 tile, BK=64, 4 waves, reg-staged) ----------------
// A: M x K bf16 row-major. B: N x K bf16 row-major (i.e. weights pre-transposed).
// MODE 0: sectioned epilogue for the fused projection GEMM (N=2688).
// MODE 1: plain f32 out (ld=1024) for the output GEMM.
template<int MODE>
__global__ __launch_bounds__(256) void k_gemm(const unsigned short* __restrict__ A,
                                              const unsigned short* __restrict__ B,
                                              int K,
                                              float* __restrict__ dtbuf,
                                              unsigned short* __restrict__ kvbuf,
                                              unsigned short* __restrict__ rgbuf,
                                              float* __restrict__ lastbuf,
                                              float* __restrict__ cout){
  __shared__ __align__(16) unsigned short As[128*64];
  __shared__ __align__(16) unsigned short Bs[128*64];
  const int tid = threadIdx.x, w = tid>>6, l = tid&63;
  const int row0 = blockIdx.x*128, col0 = blockIdx.y*128;
  const int wm = w & 1, wn = w >> 1;
  f32x4 acc[4][4];
  #pragma unroll
  for(int i=0;i<4;i++)
    #pragma unroll
    for(int j=0;j<4;j++){ f32x4 z = {0.f,0.f,0.f,0.f}; acc[i][j] = z; }

  const int nk = K >> 6;
  uint4 ra[4], rb[4];
  // preload k-tile 0
  #pragma unroll
  for(int i=0;i<4;i++){
    int ci = tid + i*256, m = ci>>3, k8 = ci&7;
    ra[i] = *(const uint4*)&A[(size_t)(row0+m)*K + 0*64 + k8*8];
    rb[i] = *(const uint4*)&B[(size_t)(col0+m)*K + 0*64 + k8*8];
  }
  for(int kt=0; kt<nk; ++kt){
    __syncthreads();
    #pragma unroll
    for(int i=0;i<4;i++){
      int ci = tid + i*256;
      *(uint4*)&As[ci*8] = ra[i];
      *(uint4*)&Bs[ci*8] = rb[i];
    }
    __syncthreads();
    if(kt+1 < nk){
      #pragma unroll
      for(int i=0;i<4;i++){
        int ci = tid + i*256, m = ci>>3, k8 = ci&7;
        ra[i] = *(const uint4*)&A[(size_t)(row0+m)*K + (kt+1)*64 + k8*8];
        rb[i] = *(const uint4*)&B[(size_t)(col0+m)*K + (kt+1)*64 + k8*8];
      }
    }
    #pragma unroll
    for(int kk=0;kk<2;kk++){
      bf16x8 af[4], bfr[4];
      #pragma unroll
      for(int mf=0;mf<4;mf++)
        af[mf] = *(const bf16x8*)&As[(wm*64 + mf*16 + (l&15))*64 + kk*32 + (l>>4)*8];
      #pragma unroll
      for(int nf=0;nf<4;nf++)
        bfr[nf] = *(const bf16x8*)&Bs[(wn*64 + nf*16 + (l&15))*64 + kk*32 + (l>>4)*8];
      #pragma unroll
      for(int mf=0;mf<4;mf++)
        #pragma unroll
        for(int nf=0;nf<4;nf++)
          acc[mf][nf] = __builtin_amdgcn_mfma_f32_16x16x32_bf16(af[mf], bfr[nf], acc[mf][nf], 0,0,0);
    }
  }
  // epilogue
  #pragma unroll
  for(int mf=0;mf<4;mf++)
    #pragma unroll
    for(int nf=0;nf<4;nf++)
      #pragma unroll
      for(int j=0;j<4;j++){
        int gr = row0 + wm*64 + mf*16 + (l>>4)*4 + j;
        int gc = col0 + wn*64 + nf*16 + (l&15);
        float v = acc[mf][nf][j];
        if(MODE == 1){
          cout[(size_t)gr*1024 + gc] = v;
        } else {
          if(col0 < 512)        dtbuf[(size_t)gr*512  + gc]        = v;
          else if(col0 < 1536)  kvbuf[(size_t)gr*1024 + (gc-512)]  = f2bf(v);
          else if(col0 < 2560)  rgbuf[(size_t)gr*1024 + (gc-1536)] = f2bf(v);
          else                  lastbuf[(size_t)gr*128 + (gc-2560)] = v;
        }
      }
}

// ---------------- scan phase 1: per-chunk parallel ----------------
// block = (bh, c), 64 threads (lane = d).  Computes, for its 16-step chunk:
//   logd accumulation Lc; Q=k*exp(Lc); ks=k*exp(-Lc); A_c=exp(Lc[15]);
//   U[v][d] = sum_t ks[t][d]*bs[t]*v[t][v];  P[t][s]=bs[s]*sum_d q[t]ks[s] (masked);
//   intra[t][v] = sum_s P[t][s] v[s][v] + tf*k*v
__global__ __launch_bounds__(64) void k_scan1(const float* __restrict__ dtbuf,
                                              const unsigned short* __restrict__ kvbuf,
                                              const float* __restrict__ lastbuf,
                                              const float* __restrict__ base_decay,
                                              const float* __restrict__ dt_b,
                                              const float* __restrict__ time_first,
                                              unsigned short* __restrict__ wsQ,
                                              unsigned short* __restrict__ wsI,
                                              unsigned short* __restrict__ wsU,
                                              float* __restrict__ wsA){
  const int bx = blockIdx.x;             // bh*NC + c
  const int c = bx & (NC-1), bh = bx >> 8;
  const int b = bh >> 3, h = bh & 7;
  const int d = threadIdx.x;
  const int rowbase = b*SEQ + c*CT;
  const int hd = h*64 + d;

  __shared__ float vsm[16][68];
  __shared__ float qsm[16][68];
  __shared__ float ksm[16][68];
  __shared__ float Ps[16][20];
  __shared__ float bsL[16];

  const float rate = base_decay[hd], dtb = dt_b[hd], tfv = time_first[hd];

  float kreg[16], vreg[16], kb[16];
  float run = 0.f;
  #pragma unroll
  for(int t=0;t<16;t++){
    int row = rowbase + t;
    float xdt = dtbuf[(size_t)row*512 + hd] + dtb;
    float sp = (xdt > 30.f) ? xdt : log1pf(expf(xdt));   // softplus
    run -= rate*sp;
    float ep = expf(run), em = expf(-run);
    kreg[t] = bf2f(kvbuf[(size_t)row*1024 + hd]);
    vreg[t] = bf2f(kvbuf[(size_t)row*1024 + 512 + hd]);
    float bs = lastbuf[(size_t)row*128];
    float q  = kreg[t]*ep;
    float ks = kreg[t]*em;
    kb[t] = ks*bs;
    wsQ[(size_t)row*512 + hd] = f2bf(q);
    vsm[t][d] = vreg[t];
    qsm[t][d] = q;
    ksm[t][d] = ks;
    if(d == 0) bsL[t] = bs;
  }
  wsA[(size_t)bx*64 + d] = expf(run);
  __syncthreads();

  // U[v][d] stores (layout [c][v][d])
  #pragma unroll 4
  for(int vc=0; vc<16; vc++){
    float u0=0,u1=0,u2=0,u3=0;
    #pragma unroll
    for(int t=0;t<16;t++){
      float4 v4 = *(const float4*)&vsm[t][vc*4];
      u0 += kb[t]*v4.x; u1 += kb[t]*v4.y; u2 += kb[t]*v4.z; u3 += kb[t]*v4.w;
    }
    size_t ub = (size_t)bx*4096 + (size_t)(vc*4)*64 + d;
    wsU[ub]       = f2bf(u0);
    wsU[ub+64]    = f2bf(u1);
    wsU[ub+128]   = f2bf(u2);
    wsU[ub+192]   = f2bf(u3);
  }

  // P[t][s]
  {
    const int tt = d >> 2, s0 = d & 3;
    #pragma unroll
    for(int ss=0; ss<4; ss++){
      int s = s0 + ss*4;
      float dot = 0.f;
      #pragma unroll
      for(int dc=0; dc<16; dc++){
        float4 a4 = *(const float4*)&qsm[tt][dc*4];
        float4 b4 = *(const float4*)&ksm[s][dc*4];
        dot += a4.x*b4.x + a4.y*b4.y + a4.z*b4.z + a4.w*b4.w;
      }
      Ps[tt][s] = (s <= tt) ? dot*bsL[s] : 0.f;
    }
  }
  __syncthreads();

  // intra output (lane = v now; vreg/kreg are v[t][lane], k[t][lane])
  #pragma unroll 1
  for(int t=0;t<16;t++){
    float acc = tfv*kreg[t]*vreg[t];
    #pragma unroll
    for(int s=0;s<16;s++) acc += Ps[t][s]*vreg[s];
    int row = rowbase + t;
    wsI[(size_t)row*512 + hd] = f2bf(acc);
  }
}

// ---------------- scan phase 2: sequential state recurrence ----------------
// grid (32 bh, 4 vq) x 256 threads; thread owns (v, d0..d0+3).
// st <- A_c * (st + U_c); writes state ENTERING chunk c back into U buffer (bf16).
__global__ __launch_bounds__(256) void k_scan2(unsigned short* __restrict__ US,
                                               const float* __restrict__ wsA,
                                               float* __restrict__ outState){
  const int bh = blockIdx.x, vq = blockIdx.y;
  const int t = threadIdx.x;
  const int v = vq*16 + (t>>4);
  const int d0 = (t & 15)*4;
  const size_t ubase = (size_t)bh*NC*4096 + (size_t)v*64 + d0;
  const size_t abase = (size_t)bh*NC*64 + d0;
  float st0=0.f, st1=0.f, st2=0.f, st3=0.f;
  ushort4 ua[8], ub[8]; float4 aa[8], ab[8];
  #pragma unroll
  for(int i=0;i<8;i++){
    ua[i] = *(const ushort4*)&US[ubase + (size_t)i*4096];
    aa[i] = *(const float4*)&wsA[abase + (size_t)i*64];
  }
  for(int g=0; g<32; g+=2){
    #pragma unroll
    for(int i=0;i<8;i++){
      int c = (g+1)*8 + i;
      ub[i] = *(const ushort4*)&US[ubase + (size_t)c*4096];
      ab[i] = *(const float4*)&wsA[abase + (size_t)c*64];
    }
    #pragma unroll
    for(int i=0;i<8;i++){
      int c = g*8 + i;
      ushort4 sw; sw.x=f2bf(st0); sw.y=f2bf(st1); sw.z=f2bf(st2); sw.w=f2bf(st3);
      *(ushort4*)&US[ubase + (size_t)c*4096] = sw;
      st0 = aa[i].x*(st0 + bf2f(ua[i].x));
      st1 = aa[i].y*(st1 + bf2f(ua[i].y));
      st2 = aa[i].z*(st2 + bf2f(ua[i].z));
      st3 = aa[i].w*(st3 + bf2f(ua[i].w));
    }
    if(g+2 < 32){
      #pragma unroll
      for(int i=0;i<8;i++){
        int c = (g+2)*8 + i;
        ua[i] = *(const ushort4*)&US[ubase + (size_t)c*4096];
        aa[i] = *(const float4*)&wsA[abase + (size_t)c*64];
      }
    }
    #pragma unroll
    for(int i=0;i<8;i++){
      int c = (g+1)*8 + i;
      ushort4 sw; sw.x=f2bf(st0); sw.y=f2bf(st1); sw.z=f2bf(st2); sw.w=f2bf(st3);
      *(ushort4*)&US[ubase + (size_t)c*4096] = sw;
      st0 = ab[i].x*(st0 + bf2f(ub[i].x));
      st1 = ab[i].y*(st1 + bf2f(ub[i].y));
      st2 = ab[i].z*(st2 + bf2f(ub[i].z));
      st3 = ab[i].w*(st3 + bf2f(ub[i].w));
    }
  }
  #pragma unroll
  for(int j=0;j<4;j++)
    outState[(size_t)bh*4096 + (size_t)(d0+j)*64 + v] = (j==0)?st0:((j==1)?st1:((j==2)?st2:st3));
}

// ---------------- scan phase 3: per-chunk outputs ----------------
// block = (bh, c), 64 threads (lane = v): wkv = Q@st_prev + intra; y = sig(r)*wkv*sig(g)
__global__ __launch_bounds__(64) void k_out(const unsigned short* __restrict__ wsQ,
                                            const unsigned short* __restrict__ wsI,
                                            const unsigned short* __restrict__ states,
                                            const unsigned short* __restrict__ rgbuf,
                                            unsigned short* __restrict__ ys){
  const int bx = blockIdx.x;
  const int c = bx & (NC-1), bh = bx >> 8;
  const int b = bh >> 3, h = bh & 7;
  const int lane = threadIdx.x;
  const int rowbase = b*SEQ + c*CT;
  __shared__ float qL[16][68];
  #pragma unroll
  for(int t=0;t<16;t++)
    qL[t][lane] = bf2f(wsQ[(size_t)(rowbase+t)*512 + h*64 + lane]);
  float stv[64];
  {
    const unsigned short* sp = &states[(size_t)bx*4096 + (size_t)lane*64];
    #pragma unroll
    for(int dd=0; dd<16; dd++){
      ushort4 u = *(const ushort4*)&sp[dd*4];
      stv[dd*4+0]=bf2f(u.x); stv[dd*4+1]=bf2f(u.y); stv[dd*4+2]=bf2f(u.z); stv[dd*4+3]=bf2f(u.w);
    }
  }
  __syncthreads();
  #pragma unroll 1
  for(int t=0;t<16;t++){
    float w = 0.f;
    #pragma unroll
    for(int dc=0; dc<16; dc++){
      float4 q4 = *(const float4*)&qL[t][dc*4];
      w += q4.x*stv[dc*4] + q4.y*stv[dc*4+1] + q4.z*stv[dc*4+2] + q4.w*stv[dc*4+3];
    }
    int row = rowbase + t;
    float intra = bf2f(wsI[(size_t)row*512 + h*64 + lane]);
    float rr = bf2f(rgbuf[(size_t)row*1024 + h*64 + lane]);
    float gg = bf2f(rgbuf[(size_t)row*1024 + 512 + h*64 + lane]);
    rr = 1.f/(1.f + expf(-rr));
    gg = 1.f/(1.f + expf(-gg));
    float y = rr*(w + intra)*gg;
    ys[(size_t)row*512 + h*64 + lane] = f2bf(y);
  }
}

// ---------------- launcher ----------------
extern "C" void kernel_launch(void* const* d_in, const int* in_sizes, int n_in,
                              void* d_out, int out_size, void* d_ws, size_t ws_size,
                              hipStream_t stream){
  const float* x          = (const float*)d_in[0];
  const float* W_sel      = (const float*)d_in[1];
  const float* dt_W       = (const float*)d_in[2];
  const float* dt_b       = (const float*)d_in[3];
  const float* Wk         = (const float*)d_in[4];
  const float* Wv         = (const float*)d_in[5];
  const float* Wr         = (const float*)d_in[6];
  const float* Wg         = (const float*)d_in[7];
  const float* Wo         = (const float*)d_in[8];
  const float* base_decay = (const float*)d_in[9];
  const float* time_first = (const float*)d_in[10];
  float* out = (float*)d_out;

  char* wsb = (char*)d_ws;
  // ws layout (bytes). Overlays: wsQ/wsI reuse Xbf (dead after GEMM1);
  // ys reuses dtbuf (dead after scan1); states reuse wsU (rewritten in scan2).
  unsigned short* Xbf   = (unsigned short*)(wsb + 0);          // 33,554,432
  unsigned short* wsQ   = (unsigned short*)(wsb + 0);          // 16,777,216 (overlay)
  unsigned short* wsI   = (unsigned short*)(wsb + 16777216);   // 16,777,216 (overlay)
  unsigned short* Wcat  = (unsigned short*)(wsb + 33554432);   //  5,505,024  (2688 x 1024 bf16)
  unsigned short* WoT   = (unsigned short*)(wsb + 39059456);   //  1,048,576  (1024 x 512 bf16)
  float*          dtbuf = (float*)         (wsb + 40108032);   // 33,554,432  (16384 x 512 f32)
  unsigned short* ys    = (unsigned short*)(wsb + 40108032);   // 16,777,216 (overlay)
  unsigned short* kvbuf = (unsigned short*)(wsb + 73662464);   // 33,554,432  (16384 x 1024 bf16)
  unsigned short* rgbuf = (unsigned short*)(wsb + 107216896);  // 33,554,432
  float*          lastb = (float*)         (wsb + 140771328);  //  8,388,608  (16384 x 128 f32)
  unsigned short* wsU   = (unsigned short*)(wsb + 149159936);  // 67,108,864  (8192 x 4096 bf16)
  float*          wsA   = (float*)         (wsb + 216268800);  //  2,097,152
  // total: 218,365,952 bytes

  k_prep_x<<<dim3(8192), dim3(256), 0, stream>>>(x, Xbf);
  k_prep_dteff<<<dim3(2048), dim3(256), 0, stream>>>(W_sel, dt_W, Wcat);
  k_transpose<<<dim3(32,16), dim3(256), 0, stream>>>(Wk, Wcat + (size_t)512*1024,  1024, 512);
  k_transpose<<<dim3(32,16), dim3(256), 0, stream>>>(Wv, Wcat + (size_t)1024*1024, 1024, 512);
  k_transpose<<<dim3(32,16), dim3(256), 0, stream>>>(Wr, Wcat + (size_t)1536*1024, 1024, 512);
  k_transpose<<<dim3(32,16), dim3(256), 0, stream>>>(Wg, Wcat + (size_t)2048*1024, 1024, 512);
  k_transpose<<<dim3(16,32), dim3(256), 0, stream>>>(Wo, WoT, 512, 1024);
  k_prep_wbs<<<dim3(4), dim3(256), 0, stream>>>(W_sel, Wcat);
  hipMemsetAsync(Wcat + (size_t)2561*1024, 0, (size_t)127*1024*2, stream);

  k_gemm<0><<<dim3(128,21), dim3(256), 0, stream>>>(Xbf, Wcat, 1024, dtbuf, kvbuf, rgbuf, lastb, nullptr);

  k_scan1<<<dim3(8192), dim3(64), 0, stream>>>(dtbuf, kvbuf, lastb, base_decay, dt_b, time_first,
                                               wsQ, wsI, wsU, wsA);
  k_scan2<<<dim3(32,4), dim3(256), 0, stream>>>(wsU, wsA, out + 16777216);
  k_out<<<dim3(8192), dim3(64), 0, stream>>>(wsQ, wsI, wsU, rgbuf, ys);

  k_gemm<1><<<dim3(128,8), dim3(256), 0, stream>>>(ys, WoT, 512, nullptr, nullptr, nullptr, nullptr, out);
}

// Round 5
// 511.304 us; speedup vs baseline: 1.6861x; 1.6861x over previous
//
#include <hip/hip_runtime.h>
#include <hip/hip_bf16.h>
#include <stdint.h>

// Problem constants
#define ROWS 16384      // B*L
#define SEQ  4096
#define CT   16         // chunk length
#define NC   256        // chunks per sequence
#define NBH  32         // B*NUM_HEADS

typedef __attribute__((ext_vector_type(8))) short bf16x8;
typedef __attribute__((ext_vector_type(4))) float f32x4;

__device__ __forceinline__ float bf2f(unsigned short u){
  unsigned int x = ((unsigned int)u) << 16;
  float f; __builtin_memcpy(&f, &x, 4); return f;
}
__device__ __forceinline__ unsigned short f2bf(float f){
  __hip_bfloat16 h = __float2bfloat16(f);
  unsigned short u; __builtin_memcpy(&u, &h, 2); return u;
}

// async global->LDS, 16B per lane; LDS dest = wave-uniform base + lane*16 (linear!)
__device__ __forceinline__ void gload16(const unsigned short* g, unsigned short* l){
  __builtin_amdgcn_global_load_lds((const __attribute__((address_space(1))) unsigned int*)g,
                                   (__attribute__((address_space(3))) unsigned int*)l, 16, 0, 0);
}

// ---------------- prep kernels ----------------

// x (f32) -> bf16, 8 elems/thread
__global__ __launch_bounds__(256) void k_prep_x(const float* __restrict__ x,
                                                unsigned short* __restrict__ xbf){
  int id = blockIdx.x*256 + threadIdx.x;         // 2,097,152 threads
  const float4* in = (const float4*)x;
  float4 a = in[(size_t)id*2], b = in[(size_t)id*2+1];
  union { unsigned short s[8]; uint4 v; } u;
  u.s[0]=f2bf(a.x); u.s[1]=f2bf(a.y); u.s[2]=f2bf(a.z); u.s[3]=f2bf(a.w);
  u.s[4]=f2bf(b.x); u.s[5]=f2bf(b.y); u.s[6]=f2bf(b.z); u.s[7]=f2bf(b.w);
  ((uint4*)xbf)[id] = u.v;
}

// W_dt_eff^T = (W_sel[:, :32] @ dt_W)^T  -> Wcat rows [0,512)
__global__ __launch_bounds__(256) void k_prep_dteff(const float* __restrict__ Wsel,
                                                    const float* __restrict__ dtW,
                                                    unsigned short* __restrict__ wcat){
  int id = blockIdx.x*256 + threadIdx.x;         // 524288
  int n = id >> 10, kk = id & 1023;
  float acc = 0.f;
  #pragma unroll
  for(int j=0;j<32;j++) acc += Wsel[kk*160 + j] * dtW[j*512 + n];
  wcat[(size_t)n*1024 + kk] = f2bf(acc);
}

// w_bs = mean over W_sel[:,32:96] -> Wcat row 2560
__global__ __launch_bounds__(256) void k_prep_wbs(const float* __restrict__ Wsel,
                                                  unsigned short* __restrict__ wcat){
  int kk = blockIdx.x*256 + threadIdx.x;         // 1024
  float acc = 0.f;
  #pragma unroll
  for(int j=0;j<64;j++) acc += Wsel[kk*160 + 32 + j];
  wcat[(size_t)2560*1024 + kk] = f2bf(acc * (1.0f/64.0f));
}

// src[R][C] f32 -> dst[C][R] bf16 (tiled transpose)
__global__ __launch_bounds__(256) void k_transpose(const float* __restrict__ src,
                                                   unsigned short* __restrict__ dst,
                                                   int R, int C){
  __shared__ float tile[32][33];
  int tx = threadIdx.x & 31, ty = threadIdx.x >> 5;
  int r0 = blockIdx.x*32, c0 = blockIdx.y*32;
  #pragma unroll
  for(int i=0;i<4;i++) tile[ty+i*8][tx] = src[(size_t)(r0+ty+i*8)*C + c0+tx];
  __syncthreads();
  #pragma unroll
  for(int i=0;i<4;i++) dst[(size_t)(c0+ty+i*8)*R + r0+tx] = f2bf(tile[tx][ty+i*8]);
}

// ---------------- GEMM (128x128 tile, BK=64, 4 waves, global_load_lds) --------
// m97 structure: per K-step { barrier; stage A+B via global_load_lds(16B);
// barrier (vmcnt drain); swizzled ds_read_b128 frags; 16 MFMA }.
// LDS swizzle: physical chunk p (16B) of row r holds logical chunk p ^ (r&7).
// Staging pre-swizzles the GLOBAL source (rule #21); reads apply the same XOR.
// A: M x K bf16 row-major. B: N x K bf16 row-major (weights pre-transposed).
// MODE 0: sectioned epilogue (N=2688). MODE 1: plain f32 out ld=1024 (N=1024).
template<int MODE>
__global__ __launch_bounds__(256) void k_gemm(const unsigned short* __restrict__ A,
                                              const unsigned short* __restrict__ B,
                                              int K, int ncols,
                                              float* __restrict__ dtbuf,
                                              unsigned short* __restrict__ kvbuf,
                                              unsigned short* __restrict__ rgbuf,
                                              float* __restrict__ lastbuf,
                                              float* __restrict__ cout){
  __shared__ __align__(16) unsigned short As[128*64];
  __shared__ __align__(16) unsigned short Bs[128*64];
  const int tid = threadIdx.x, w = tid>>6, l = tid&63;

  // XCD-chunked bijective swizzle (gridDim.x % 8 == 0), cols-fastest so the
  // ncols blocks sharing one A row-panel are adjacent in dispatch order.
  int orig = blockIdx.x;
  int q = gridDim.x >> 3;
  int swz = (orig & 7)*q + (orig >> 3);
  const int row0 = (swz / ncols)*128, col0 = (swz % ncols)*128;

  const int wm = w & 1, wn = w >> 1;
  f32x4 acc[4][4];
  #pragma unroll
  for(int i=0;i<4;i++)
    #pragma unroll
    for(int j=0;j<4;j++){ f32x4 z = {0.f,0.f,0.f,0.f}; acc[i][j] = z; }

  const int nk = K >> 6;
  const int lr = l >> 3;                    // lane row within 8-row group
  const int lc = ((l & 7) ^ lr) * 8;        // pre-swizzled element col (16B chunks)

  for(int kt=0; kt<nk; ++kt){
    __syncthreads();
    #pragma unroll
    for(int i=0;i<4;i++){
      int r = w*32 + i*8;
      gload16(&A[(size_t)(row0 + r + lr)*K + kt*64 + lc], &As[r*64]);
      gload16(&B[(size_t)(col0 + r + lr)*K + kt*64 + lc], &Bs[r*64]);
    }
    asm volatile("s_waitcnt vmcnt(0)");
    __syncthreads();
    #pragma unroll
    for(int kk=0;kk<2;kk++){
      bf16x8 af[4], bfr[4];
      const int pb = (kk*64 + (l>>4)*16) ^ ((l&7)<<4);   // swizzled byte col
      #pragma unroll
      for(int mf=0;mf<4;mf++){
        int row = wm*64 + mf*16 + (l&15);
        af[mf] = *(const bf16x8*)((const char*)As + row*128 + pb);
      }
      #pragma unroll
      for(int nf=0;nf<4;nf++){
        int row = wn*64 + nf*16 + (l&15);
        bfr[nf] = *(const bf16x8*)((const char*)Bs + row*128 + pb);
      }
      #pragma unroll
      for(int mf=0;mf<4;mf++)
        #pragma unroll
        for(int nf=0;nf<4;nf++)
          acc[mf][nf] = __builtin_amdgcn_mfma_f32_16x16x32_bf16(af[mf], bfr[nf], acc[mf][nf], 0,0,0);
    }
  }
  // epilogue
  #pragma unroll
  for(int mf=0;mf<4;mf++)
    #pragma unroll
    for(int nf=0;nf<4;nf++)
      #pragma unroll
      for(int j=0;j<4;j++){
        int gr = row0 + wm*64 + mf*16 + (l>>4)*4 + j;
        int gc = col0 + wn*64 + nf*16 + (l&15);
        float v = acc[mf][nf][j];
        if(MODE == 1){
          cout[(size_t)gr*1024 + gc] = v;
        } else {
          if(col0 < 512)        dtbuf[(size_t)gr*512  + gc]        = v;
          else if(col0 < 1536)  kvbuf[(size_t)gr*1024 + (gc-512)]  = f2bf(v);
          else if(col0 < 2560)  rgbuf[(size_t)gr*1024 + (gc-1536)] = f2bf(v);
          else if(gc == 2560)   lastbuf[gr] = v;   // compact bscale column
        }
      }
}

// ---------------- scan phase 1: per-chunk parallel ----------------
// block = (bh, c), 64 threads (lane = d).  Computes, for its 16-step chunk:
//   logd accumulation Lc; Q=k*exp(Lc); ks=k*exp(-Lc); A_c=exp(Lc[15]);
//   U[v][d] = sum_t ks[t][d]*bs[t]*v[t][v];  P[t][s]=bs[s]*sum_d q[t]ks[s] (masked);
//   intra[t][v] = sum_s P[t][s] v[s][v] + tf*k*v
__global__ __launch_bounds__(64) void k_scan1(const float* __restrict__ dtbuf,
                                              const unsigned short* __restrict__ kvbuf,
                                              const float* __restrict__ lastbuf,
                                              const float* __restrict__ base_decay,
                                              const float* __restrict__ dt_b,
                                              const float* __restrict__ time_first,
                                              unsigned short* __restrict__ wsQ,
                                              unsigned short* __restrict__ wsI,
                                              unsigned short* __restrict__ wsU,
                                              float* __restrict__ wsA){
  const int bx = blockIdx.x;             // bh*NC + c
  const int c = bx & (NC-1), bh = bx >> 8;
  const int b = bh >> 3, h = bh & 7;
  const int d = threadIdx.x;
  const int rowbase = b*SEQ + c*CT;
  const int hd = h*64 + d;

  __shared__ float vsm[16][68];
  __shared__ float qsm[16][68];
  __shared__ float ksm[16][68];
  __shared__ float Ps[16][20];
  __shared__ float bsL[16];

  const float rate = base_decay[hd], dtb = dt_b[hd], tfv = time_first[hd];

  float kreg[16], vreg[16], kb[16];
  float run = 0.f;
  #pragma unroll
  for(int t=0;t<16;t++){
    int row = rowbase + t;
    float xdt = dtbuf[(size_t)row*512 + hd] + dtb;
    float sp = (xdt > 30.f) ? xdt : log1pf(expf(xdt));   // softplus
    run -= rate*sp;
    float ep = expf(run), em = expf(-run);
    kreg[t] = bf2f(kvbuf[(size_t)row*1024 + hd]);
    vreg[t] = bf2f(kvbuf[(size_t)row*1024 + 512 + hd]);
    float bs = lastbuf[row];
    float q  = kreg[t]*ep;
    float ks = kreg[t]*em;
    kb[t] = ks*bs;
    wsQ[(size_t)row*512 + hd] = f2bf(q);
    vsm[t][d] = vreg[t];
    qsm[t][d] = q;
    ksm[t][d] = ks;
    if(d == 0) bsL[t] = bs;
  }
  wsA[(size_t)bx*64 + d] = expf(run);
  __syncthreads();

  // U[v][d] stores (layout [c][v][d])
  #pragma unroll 4
  for(int vc=0; vc<16; vc++){
    float u0=0,u1=0,u2=0,u3=0;
    #pragma unroll
    for(int t=0;t<16;t++){
      float4 v4 = *(const float4*)&vsm[t][vc*4];
      u0 += kb[t]*v4.x; u1 += kb[t]*v4.y; u2 += kb[t]*v4.z; u3 += kb[t]*v4.w;
    }
    size_t ub = (size_t)bx*4096 + (size_t)(vc*4)*64 + d;
    wsU[ub]       = f2bf(u0);
    wsU[ub+64]    = f2bf(u1);
    wsU[ub+128]   = f2bf(u2);
    wsU[ub+192]   = f2bf(u3);
  }

  // P[t][s]
  {
    const int tt = d >> 2, s0 = d & 3;
    #pragma unroll
    for(int ss=0; ss<4; ss++){
      int s = s0 + ss*4;
      float dot = 0.f;
      #pragma unroll
      for(int dc=0; dc<16; dc++){
        float4 a4 = *(const float4*)&qsm[tt][dc*4];
        float4 b4 = *(const float4*)&ksm[s][dc*4];
        dot += a4.x*b4.x + a4.y*b4.y + a4.z*b4.z + a4.w*b4.w;
      }
      Ps[tt][s] = (s <= tt) ? dot*bsL[s] : 0.f;
    }
  }
  __syncthreads();

  // intra output (lane = v now; vreg/kreg are v[t][lane], k[t][lane])
  #pragma unroll 1
  for(int t=0;t<16;t++){
    float acc = tfv*kreg[t]*vreg[t];
    #pragma unroll
    for(int s=0;s<16;s++) acc += Ps[t][s]*vreg[s];
    int row = rowbase + t;
    wsI[(size_t)row*512 + hd] = f2bf(acc);
  }
}

// ---------------- scan phase 2: sequential state recurrence ----------------
// grid (32 bh, 4 vq) x 256 threads; thread owns (v, d0..d0+3).
// st <- A_c * (st + U_c); writes state ENTERING chunk c back into U buffer (bf16).
__global__ __launch_bounds__(256) void k_scan2(unsigned short* __restrict__ US,
                                               const float* __restrict__ wsA,
                                               float* __restrict__ outState){
  const int bh = blockIdx.x, vq = blockIdx.y;
  const int t = threadIdx.x;
  const int v = vq*16 + (t>>4);
  const int d0 = (t & 15)*4;
  const size_t ubase = (size_t)bh*NC*4096 + (size_t)v*64 + d0;
  const size_t abase = (size_t)bh*NC*64 + d0;
  float st0=0.f, st1=0.f, st2=0.f, st3=0.f;
  ushort4 ua[8], ub[8]; float4 aa[8], ab[8];
  #pragma unroll
  for(int i=0;i<8;i++){
    ua[i] = *(const ushort4*)&US[ubase + (size_t)i*4096];
    aa[i] = *(const float4*)&wsA[abase + (size_t)i*64];
  }
  for(int g=0; g<32; g+=2){
    #pragma unroll
    for(int i=0;i<8;i++){
      int c = (g+1)*8 + i;
      ub[i] = *(const ushort4*)&US[ubase + (size_t)c*4096];
      ab[i] = *(const float4*)&wsA[abase + (size_t)c*64];
    }
    #pragma unroll
    for(int i=0;i<8;i++){
      int c = g*8 + i;
      ushort4 sw; sw.x=f2bf(st0); sw.y=f2bf(st1); sw.z=f2bf(st2); sw.w=f2bf(st3);
      *(ushort4*)&US[ubase + (size_t)c*4096] = sw;
      st0 = aa[i].x*(st0 + bf2f(ua[i].x));
      st1 = aa[i].y*(st1 + bf2f(ua[i].y));
      st2 = aa[i].z*(st2 + bf2f(ua[i].z));
      st3 = aa[i].w*(st3 + bf2f(ua[i].w));
    }
    if(g+2 < 32){
      #pragma unroll
      for(int i=0;i<8;i++){
        int c = (g+2)*8 + i;
        ua[i] = *(const ushort4*)&US[ubase + (size_t)c*4096];
        aa[i] = *(const float4*)&wsA[abase + (size_t)c*64];
      }
    }
    #pragma unroll
    for(int i=0;i<8;i++){
      int c = (g+1)*8 + i;
      ushort4 sw; sw.x=f2bf(st0); sw.y=f2bf(st1); sw.z=f2bf(st2); sw.w=f2bf(st3);
      *(ushort4*)&US[ubase + (size_t)c*4096] = sw;
      st0 = ab[i].x*(st0 + bf2f(ub[i].x));
      st1 = ab[i].y*(st1 + bf2f(ub[i].y));
      st2 = ab[i].z*(st2 + bf2f(ub[i].z));
      st3 = ab[i].w*(st3 + bf2f(ub[i].w));
    }
  }
  #pragma unroll
  for(int j=0;j<4;j++)
    outState[(size_t)bh*4096 + (size_t)(d0+j)*64 + v] = (j==0)?st0:((j==1)?st1:((j==2)?st2:st3));
}

// ---------------- scan phase 3: per-chunk outputs ----------------
// block = (bh, c), 64 threads (lane = v): wkv = Q@st_prev + intra; y = sig(r)*wkv*sig(g)
__global__ __launch_bounds__(64) void k_out(const unsigned short* __restrict__ wsQ,
                                            const unsigned short* __restrict__ wsI,
                                            const unsigned short* __restrict__ states,
                                            const unsigned short* __restrict__ rgbuf,
                                            unsigned short* __restrict__ ys){
  const int bx = blockIdx.x;
  const int c = bx & (NC-1), bh = bx >> 8;
  const int b = bh >> 3, h = bh & 7;
  const int lane = threadIdx.x;
  const int rowbase = b*SEQ + c*CT;
  __shared__ float qL[16][68];
  #pragma unroll
  for(int t=0;t<16;t++)
    qL[t][lane] = bf2f(wsQ[(size_t)(rowbase+t)*512 + h*64 + lane]);
  float stv[64];
  {
    const unsigned short* sp = &states[(size_t)bx*4096 + (size_t)lane*64];
    #pragma unroll
    for(int dd=0; dd<16; dd++){
      ushort4 u = *(const ushort4*)&sp[dd*4];
      stv[dd*4+0]=bf2f(u.x); stv[dd*4+1]=bf2f(u.y); stv[dd*4+2]=bf2f(u.z); stv[dd*4+3]=bf2f(u.w);
    }
  }
  __syncthreads();
  #pragma unroll 1
  for(int t=0;t<16;t++){
    float w = 0.f;
    #pragma unroll
    for(int dc=0; dc<16; dc++){
      float4 q4 = *(const float4*)&qL[t][dc*4];
      w += q4.x*stv[dc*4] + q4.y*stv[dc*4+1] + q4.z*stv[dc*4+2] + q4.w*stv[dc*4+3];
    }
    int row = rowbase + t;
    float intra = bf2f(wsI[(size_t)row*512 + h*64 + lane]);
    float rr = bf2f(rgbuf[(size_t)row*1024 + h*64 + lane]);
    float gg = bf2f(rgbuf[(size_t)row*1024 + 512 + h*64 + lane]);
    rr = 1.f/(1.f + expf(-rr));
    gg = 1.f/(1.f + expf(-gg));
    float y = rr*(w + intra)*gg;
    ys[(size_t)row*512 + h*64 + lane] = f2bf(y);
  }
}

// ---------------- launcher ----------------
extern "C" void kernel_launch(void* const* d_in, const int* in_sizes, int n_in,
                              void* d_out, int out_size, void* d_ws, size_t ws_size,
                              hipStream_t stream){
  const float* x          = (const float*)d_in[0];
  const float* W_sel      = (const float*)d_in[1];
  const float* dt_W       = (const float*)d_in[2];
  const float* dt_b       = (const float*)d_in[3];
  const float* Wk         = (const float*)d_in[4];
  const float* Wv         = (const float*)d_in[5];
  const float* Wr         = (const float*)d_in[6];
  const float* Wg         = (const float*)d_in[7];
  const float* Wo         = (const float*)d_in[8];
  const float* base_decay = (const float*)d_in[9];
  const float* time_first = (const float*)d_in[10];
  float* out = (float*)d_out;

  char* wsb = (char*)d_ws;
  // ws layout (bytes). Overlays: wsQ/wsI reuse Xbf (dead after GEMM1);
  // ys reuses dtbuf (dead after scan1); states reuse wsU (rewritten in scan2).
  unsigned short* Xbf   = (unsigned short*)(wsb + 0);          // 33,554,432
  unsigned short* wsQ   = (unsigned short*)(wsb + 0);          // 16,777,216 (overlay)
  unsigned short* wsI   = (unsigned short*)(wsb + 16777216);   // 16,777,216 (overlay)
  unsigned short* Wcat  = (unsigned short*)(wsb + 33554432);   //  5,505,024  (2688 x 1024 bf16)
  unsigned short* WoT   = (unsigned short*)(wsb + 39059456);   //  1,048,576  (1024 x 512 bf16)
  float*          dtbuf = (float*)         (wsb + 40108032);   // 33,554,432  (16384 x 512 f32)
  unsigned short* ys    = (unsigned short*)(wsb + 40108032);   // 16,777,216 (overlay)
  unsigned short* kvbuf = (unsigned short*)(wsb + 73662464);   // 33,554,432  (16384 x 1024 bf16)
  unsigned short* rgbuf = (unsigned short*)(wsb + 107216896);  // 33,554,432
  float*          lastb = (float*)         (wsb + 140771328);  //  8,388,608 region (uses 64KB, compact [row])
  unsigned short* wsU   = (unsigned short*)(wsb + 149159936);  // 67,108,864  (8192 x 4096 bf16)
  float*          wsA   = (float*)         (wsb + 216268800);  //  2,097,152
  // total: 218,365,952 bytes

  k_prep_x<<<dim3(8192), dim3(256), 0, stream>>>(x, Xbf);
  k_prep_dteff<<<dim3(2048), dim3(256), 0, stream>>>(W_sel, dt_W, Wcat);
  k_transpose<<<dim3(32,16), dim3(256), 0, stream>>>(Wk, Wcat + (size_t)512*1024,  1024, 512);
  k_transpose<<<dim3(32,16), dim3(256), 0, stream>>>(Wv, Wcat + (size_t)1024*1024, 1024, 512);
  k_transpose<<<dim3(32,16), dim3(256), 0, stream>>>(Wr, Wcat + (size_t)1536*1024, 1024, 512);
  k_transpose<<<dim3(32,16), dim3(256), 0, stream>>>(Wg, Wcat + (size_t)2048*1024, 1024, 512);
  k_transpose<<<dim3(16,32), dim3(256), 0, stream>>>(Wo, WoT, 512, 1024);
  k_prep_wbs<<<dim3(4), dim3(256), 0, stream>>>(W_sel, Wcat);
  hipMemsetAsync(Wcat + (size_t)2561*1024, 0, (size_t)127*1024*2, stream);

  // fused projection GEMM: 2688 tiles = 128 row-panels x 21 col-tiles
  k_gemm<0><<<dim3(2688), dim3(256), 0, stream>>>(Xbf, Wcat, 1024, 21, dtbuf, kvbuf, rgbuf, lastb, nullptr);

  k_scan1<<<dim3(8192), dim3(64), 0, stream>>>(dtbuf, kvbuf, lastb, base_decay, dt_b, time_first,
                                               wsQ, wsI, wsU, wsA);
  k_scan2<<<dim3(32,4), dim3(256), 0, stream>>>(wsU, wsA, out + 16777216);
  k_out<<<dim3(8192), dim3(64), 0, stream>>>(wsQ, wsI, wsU, rgbuf, ys);

  // output GEMM: 1024 tiles = 128 row-panels x 8 col-tiles
  k_gemm<1><<<dim3(1024), dim3(256), 0, stream>>>(ys, WoT, 512, 8, nullptr, nullptr, nullptr, nullptr, out);
}

// Round 10
// 465.658 us; speedup vs baseline: 1.8514x; 1.0980x over previous
//
#include <hip/hip_runtime.h>
#include <hip/hip_bf16.h>
#include <stdint.h>

// Problem constants
#define ROWS 16384      // B*L
#define SEQ  4096
#define CT   16         // chunk length
#define NC   256        // chunks per sequence
#define NBH  32         // B*NUM_HEADS

typedef __attribute__((ext_vector_type(8))) short bf16x8;
typedef __attribute__((ext_vector_type(4))) float f32x4;

__device__ __forceinline__ float bf2f(unsigned short u){
  unsigned int x = ((unsigned int)u) << 16;
  float f; __builtin_memcpy(&f, &x, 4); return f;
}
__device__ __forceinline__ unsigned short f2bf(float f){
  __hip_bfloat16 h = __float2bfloat16(f);
  unsigned short u; __builtin_memcpy(&u, &h, 2); return u;
}

// async global->LDS, 16B per lane; LDS dest = wave-uniform base + lane*16 (linear!)
__device__ __forceinline__ void gload16(const unsigned short* g, unsigned short* l){
  __builtin_amdgcn_global_load_lds((const __attribute__((address_space(1))) unsigned int*)g,
                                   (__attribute__((address_space(3))) unsigned int*)l, 16, 0, 0);
}

// ---------------- prep kernels ----------------

// x (f32) -> bf16, 8 elems/thread
__global__ __launch_bounds__(256) void k_prep_x(const float* __restrict__ x,
                                                unsigned short* __restrict__ xbf){
  int id = blockIdx.x*256 + threadIdx.x;         // 2,097,152 threads
  const float4* in = (const float4*)x;
  float4 a = in[(size_t)id*2], b = in[(size_t)id*2+1];
  union { unsigned short s[8]; uint4 v; } u;
  u.s[0]=f2bf(a.x); u.s[1]=f2bf(a.y); u.s[2]=f2bf(a.z); u.s[3]=f2bf(a.w);
  u.s[4]=f2bf(b.x); u.s[5]=f2bf(b.y); u.s[6]=f2bf(b.z); u.s[7]=f2bf(b.w);
  ((uint4*)xbf)[id] = u.v;
}

// W_dt_eff^T = (W_sel[:, :32] @ dt_W)^T  -> Wcat rows [0,512)
__global__ __launch_bounds__(256) void k_prep_dteff(const float* __restrict__ Wsel,
                                                    const float* __restrict__ dtW,
                                                    unsigned short* __restrict__ wcat){
  int id = blockIdx.x*256 + threadIdx.x;         // 524288
  int n = id >> 10, kk = id & 1023;
  float acc = 0.f;
  #pragma unroll
  for(int j=0;j<32;j++) acc += Wsel[kk*160 + j] * dtW[j*512 + n];
  wcat[(size_t)n*1024 + kk] = f2bf(acc);
}

// w_bs = mean over W_sel[:,32:96] -> Wcat row 2560
__global__ __launch_bounds__(256) void k_prep_wbs(const float* __restrict__ Wsel,
                                                  unsigned short* __restrict__ wcat){
  int kk = blockIdx.x*256 + threadIdx.x;         // 1024
  float acc = 0.f;
  #pragma unroll
  for(int j=0;j<64;j++) acc += Wsel[kk*160 + 32 + j];
  wcat[(size_t)2560*1024 + kk] = f2bf(acc * (1.0f/64.0f));
}

// src[R][C] f32 -> dst[C][R] bf16 (tiled transpose)
__global__ __launch_bounds__(256) void k_transpose(const float* __restrict__ src,
                                                   unsigned short* __restrict__ dst,
                                                   int R, int C){
  __shared__ float tile[32][33];
  int tx = threadIdx.x & 31, ty = threadIdx.x >> 5;
  int r0 = blockIdx.x*32, c0 = blockIdx.y*32;
  #pragma unroll
  for(int i=0;i<4;i++) tile[ty+i*8][tx] = src[(size_t)(r0+ty+i*8)*C + c0+tx];
  __syncthreads();
  #pragma unroll
  for(int i=0;i<4;i++) dst[(size_t)(c0+ty+i*8)*R + r0+tx] = f2bf(tile[tx][ty+i*8]);
}

// ---------------- GEMM (128x128 tile, BK=64, 4 waves, global_load_lds) --------
// unchanged from Round 5 (151 us, bank-conflict-free)
template<int MODE>
__global__ __launch_bounds__(256) void k_gemm(const unsigned short* __restrict__ A,
                                              const unsigned short* __restrict__ B,
                                              int K, int ncols,
                                              float* __restrict__ dtbuf,
                                              unsigned short* __restrict__ kvbuf,
                                              unsigned short* __restrict__ rgbuf,
                                              float* __restrict__ lastbuf,
                                              float* __restrict__ cout){
  __shared__ __align__(16) unsigned short As[128*64];
  __shared__ __align__(16) unsigned short Bs[128*64];
  const int tid = threadIdx.x, w = tid>>6, l = tid&63;

  int orig = blockIdx.x;
  int q = gridDim.x >> 3;
  int swz = (orig & 7)*q + (orig >> 3);
  const int row0 = (swz / ncols)*128, col0 = (swz % ncols)*128;

  const int wm = w & 1, wn = w >> 1;
  f32x4 acc[4][4];
  #pragma unroll
  for(int i=0;i<4;i++)
    #pragma unroll
    for(int j=0;j<4;j++){ f32x4 z = {0.f,0.f,0.f,0.f}; acc[i][j] = z; }

  const int nk = K >> 6;
  const int lr = l >> 3;
  const int lc = ((l & 7) ^ lr) * 8;

  for(int kt=0; kt<nk; ++kt){
    __syncthreads();
    #pragma unroll
    for(int i=0;i<4;i++){
      int r = w*32 + i*8;
      gload16(&A[(size_t)(row0 + r + lr)*K + kt*64 + lc], &As[r*64]);
      gload16(&B[(size_t)(col0 + r + lr)*K + kt*64 + lc], &Bs[r*64]);
    }
    asm volatile("s_waitcnt vmcnt(0)");
    __syncthreads();
    #pragma unroll
    for(int kk=0;kk<2;kk++){
      bf16x8 af[4], bfr[4];
      const int pb = (kk*64 + (l>>4)*16) ^ ((l&7)<<4);
      #pragma unroll
      for(int mf=0;mf<4;mf++){
        int row = wm*64 + mf*16 + (l&15);
        af[mf] = *(const bf16x8*)((const char*)As + row*128 + pb);
      }
      #pragma unroll
      for(int nf=0;nf<4;nf++){
        int row = wn*64 + nf*16 + (l&15);
        bfr[nf] = *(const bf16x8*)((const char*)Bs + row*128 + pb);
      }
      #pragma unroll
      for(int mf=0;mf<4;mf++)
        #pragma unroll
        for(int nf=0;nf<4;nf++)
          acc[mf][nf] = __builtin_amdgcn_mfma_f32_16x16x32_bf16(af[mf], bfr[nf], acc[mf][nf], 0,0,0);
    }
  }
  #pragma unroll
  for(int mf=0;mf<4;mf++)
    #pragma unroll
    for(int nf=0;nf<4;nf++)
      #pragma unroll
      for(int j=0;j<4;j++){
        int gr = row0 + wm*64 + mf*16 + (l>>4)*4 + j;
        int gc = col0 + wn*64 + nf*16 + (l&15);
        float v = acc[mf][nf][j];
        if(MODE == 1){
          cout[(size_t)gr*1024 + gc] = v;
        } else {
          if(col0 < 512)        dtbuf[(size_t)gr*512  + gc]        = v;
          else if(col0 < 1536)  kvbuf[(size_t)gr*1024 + (gc-512)]  = f2bf(v);
          else if(col0 < 2560)  rgbuf[(size_t)gr*1024 + (gc-1536)] = f2bf(v);
          else if(gc == 2560)   lastbuf[gr] = v;
        }
      }
}

// ---------------- scan phase 1: per-chunk parallel, MFMA-based ----------------
// block = (bh, c), 64 threads (1 wave). Phases:
//  load (lane=d): dt->softplus->run; q=k*e^run, ks=k*e^-run, kb=ks*bs; write wsQ.
//  pack: q_t[16][72], ks_t[16][72] (row=t, col=d); vt[64][40], kbt[64][40]
//        (row=v/d, col=t, cols16..31 zeroed); tft[16][68] = tf*k*v (lane=v).
//  P  = Q@Ks^T   (2 mfma, K=64) -> mask(s<=t)*bs[s] -> p_t[16][40] bf16 (pad zero)
//  U  = V^T@KB   (16 mfma, K=16 pad32)  -> wsU[c][v][d]
//  I  = P@V      (4 mfma, K=16 pad32) + tft -> wsI
__global__ __launch_bounds__(64) void k_scan1(const float* __restrict__ dtbuf,
                                              const unsigned short* __restrict__ kvbuf,
                                              const float* __restrict__ lastbuf,
                                              const float* __restrict__ base_decay,
                                              const float* __restrict__ dt_b,
                                              const float* __restrict__ time_first,
                                              unsigned short* __restrict__ wsQ,
                                              unsigned short* __restrict__ wsI,
                                              unsigned short* __restrict__ wsU,
                                              float* __restrict__ wsA){
  const int bx = blockIdx.x;             // bh*NC + c
  const int c = bx & (NC-1), bh = bx >> 8;
  const int b = bh >> 3, h = bh & 7;
  const int l = threadIdx.x;
  const int rowbase = b*SEQ + c*CT;
  const int hd = h*64 + l;

  __shared__ __align__(16) unsigned short q_t [16*72];
  __shared__ __align__(16) unsigned short ks_t[16*72];
  __shared__ __align__(16) unsigned short vt  [64*40];
  __shared__ __align__(16) unsigned short kbt [64*40];
  __shared__ __align__(16) unsigned short p_t [16*40];
  __shared__ float tft[16*68];
  __shared__ float bsL[16];

  const float rate = base_decay[hd], dtb = dt_b[hd], tfv = time_first[hd];

  float kreg[16], vreg[16], kb[16];
  float run = 0.f;
  #pragma unroll
  for(int t=0;t<16;t++){
    int row = rowbase + t;
    float xdt = dtbuf[(size_t)row*512 + hd] + dtb;
    float sp = (xdt > 30.f) ? xdt : log1pf(expf(xdt));   // softplus
    run -= rate*sp;
    float ep = expf(run), em = expf(-run);
    kreg[t] = bf2f(kvbuf[(size_t)row*1024 + hd]);
    vreg[t] = bf2f(kvbuf[(size_t)row*1024 + 512 + hd]);
    float bs = lastbuf[row];
    float qv  = kreg[t]*ep;
    float ks = kreg[t]*em;
    kb[t] = ks*bs;
    unsigned short qb = f2bf(qv);
    wsQ[(size_t)row*512 + hd] = qb;
    q_t [t*72 + l] = qb;
    ks_t[t*72 + l] = f2bf(ks);
    if(l == 0) bsL[t] = bs;
  }
  wsA[(size_t)bx*64 + l] = expf(run);

  // tf term in natural (lane = v) layout
  #pragma unroll
  for(int t=0;t<16;t++) tft[t*68 + l] = tfv*kreg[t]*vreg[t];

  // pack vt (V^T) and kbt (KB^T): row = lane, cols t=0..15, 16..31 zero
  {
    union { unsigned short s[16]; uint4 v4[2]; } pv, pk;
    #pragma unroll
    for(int t=0;t<16;t++){ pv.s[t]=f2bf(vreg[t]); pk.s[t]=f2bf(kb[t]); }
    uint4 z = {0,0,0,0};
    *(uint4*)&vt [l*40 + 0]  = pv.v4[0];
    *(uint4*)&vt [l*40 + 8]  = pv.v4[1];
    *(uint4*)&vt [l*40 + 16] = z;
    *(uint4*)&vt [l*40 + 24] = z;
    *(uint4*)&kbt[l*40 + 0]  = pk.v4[0];
    *(uint4*)&kbt[l*40 + 8]  = pk.v4[1];
    *(uint4*)&kbt[l*40 + 16] = z;
    *(uint4*)&kbt[l*40 + 24] = z;
    if(l < 32){                       // zero p_t cols 16..31
      int rr = l >> 1, hh = l & 1;
      *(uint4*)&p_t[rr*40 + 16 + hh*8] = z;
    }
  }
  __syncthreads();

  // P = Q @ Ks^T, mask + bscale, store to p_t
  {
    f32x4 accP = {0.f,0.f,0.f,0.f};
    #pragma unroll
    for(int kc=0;kc<2;kc++){
      bf16x8 a  = *(const bf16x8*)&q_t [(l&15)*72 + kc*32 + (l>>4)*8];
      bf16x8 bb = *(const bf16x8*)&ks_t[(l&15)*72 + kc*32 + (l>>4)*8];
      accP = __builtin_amdgcn_mfma_f32_16x16x32_bf16(a, bb, accP, 0,0,0);
    }
    const int s = l & 15;
    const float bss = bsL[s];
    #pragma unroll
    for(int r=0;r<4;r++){
      int t = (l>>4)*4 + r;
      float pv = (s <= t) ? accP[r]*bss : 0.f;
      p_t[t*40 + s] = f2bf(pv);
    }
  }
  __syncthreads();

  // fragments for U and intra
  bf16x8 va[4], kbb[4];
  #pragma unroll
  for(int i=0;i<4;i++){
    va[i]  = *(const bf16x8*)&vt [(i*16 + (l&15))*40 + (l>>4)*8];
    kbb[i] = *(const bf16x8*)&kbt[(i*16 + (l&15))*40 + (l>>4)*8];
  }
  // U[v][d] = sum_t V^T[v][t] * KB[t][d]
  f32x4 accU[4][4];
  #pragma unroll
  for(int vr=0;vr<4;vr++)
    #pragma unroll
    for(int dc=0;dc<4;dc++){
      f32x4 z = {0.f,0.f,0.f,0.f};
      accU[vr][dc] = __builtin_amdgcn_mfma_f32_16x16x32_bf16(va[vr], kbb[dc], z, 0,0,0);
    }
  // intra[t][v] = sum_s P[t][s] * V[s][v]
  f32x4 accI[4];
  {
    bf16x8 ap = *(const bf16x8*)&p_t[(l&15)*40 + (l>>4)*8];
    #pragma unroll
    for(int vc=0;vc<4;vc++){
      f32x4 z = {0.f,0.f,0.f,0.f};
      accI[vc] = __builtin_amdgcn_mfma_f32_16x16x32_bf16(ap, va[vc], z, 0,0,0);
    }
  }
  // stores
  #pragma unroll
  for(int vr=0;vr<4;vr++)
    #pragma unroll
    for(int dc=0;dc<4;dc++)
      #pragma unroll
      for(int r=0;r<4;r++){
        int v = vr*16 + (l>>4)*4 + r;
        int d = dc*16 + (l&15);
        wsU[(size_t)bx*4096 + (size_t)v*64 + d] = f2bf(accU[vr][dc][r]);
      }
  #pragma unroll
  for(int vc=0;vc<4;vc++)
    #pragma unroll
    for(int r=0;r<4;r++){
      int t = (l>>4)*4 + r;
      int v = vc*16 + (l&15);
      float val = accI[vc][r] + tft[t*68 + v];
      wsI[(size_t)(rowbase+t)*512 + h*64 + v] = f2bf(val);
    }
}

// ---------------- scan phase 2: sequential state recurrence (unchanged) -------
__global__ __launch_bounds__(256) void k_scan2(unsigned short* __restrict__ US,
                                               const float* __restrict__ wsA,
                                               float* __restrict__ outState){
  const int bh = blockIdx.x, vq = blockIdx.y;
  const int t = threadIdx.x;
  const int v = vq*16 + (t>>4);
  const int d0 = (t & 15)*4;
  const size_t ubase = (size_t)bh*NC*4096 + (size_t)v*64 + d0;
  const size_t abase = (size_t)bh*NC*64 + d0;
  float st0=0.f, st1=0.f, st2=0.f, st3=0.f;
  ushort4 ua[8], ub[8]; float4 aa[8], ab[8];
  #pragma unroll
  for(int i=0;i<8;i++){
    ua[i] = *(const ushort4*)&US[ubase + (size_t)i*4096];
    aa[i] = *(const float4*)&wsA[abase + (size_t)i*64];
  }
  for(int g=0; g<32; g+=2){
    #pragma unroll
    for(int i=0;i<8;i++){
      int c = (g+1)*8 + i;
      ub[i] = *(const ushort4*)&US[ubase + (size_t)c*4096];
      ab[i] = *(const float4*)&wsA[abase + (size_t)c*64];
    }
    #pragma unroll
    for(int i=0;i<8;i++){
      int c = g*8 + i;
      ushort4 sw; sw.x=f2bf(st0); sw.y=f2bf(st1); sw.z=f2bf(st2); sw.w=f2bf(st3);
      *(ushort4*)&US[ubase + (size_t)c*4096] = sw;
      st0 = aa[i].x*(st0 + bf2f(ua[i].x));
      st1 = aa[i].y*(st1 + bf2f(ua[i].y));
      st2 = aa[i].z*(st2 + bf2f(ua[i].z));
      st3 = aa[i].w*(st3 + bf2f(ua[i].w));
    }
    if(g+2 < 32){
      #pragma unroll
      for(int i=0;i<8;i++){
        int c = (g+2)*8 + i;
        ua[i] = *(const ushort4*)&US[ubase + (size_t)c*4096];
        aa[i] = *(const float4*)&wsA[abase + (size_t)c*64];
      }
    }
    #pragma unroll
    for(int i=0;i<8;i++){
      int c = (g+1)*8 + i;
      ushort4 sw; sw.x=f2bf(st0); sw.y=f2bf(st1); sw.z=f2bf(st2); sw.w=f2bf(st3);
      *(ushort4*)&US[ubase + (size_t)c*4096] = sw;
      st0 = ab[i].x*(st0 + bf2f(ub[i].x));
      st1 = ab[i].y*(st1 + bf2f(ub[i].y));
      st2 = ab[i].z*(st2 + bf2f(ub[i].z));
      st3 = ab[i].w*(st3 + bf2f(ub[i].w));
    }
  }
  #pragma unroll
  for(int j=0;j<4;j++)
    outState[(size_t)bh*4096 + (size_t)(d0+j)*64 + v] = (j==0)?st0:((j==1)?st1:((j==2)?st2:st3));
}

// ---------------- scan phase 3: per-chunk outputs, MFMA-based ----------------
// block = (bh, c), 64 threads. wkv = Q@st_prev (8 mfma, K=64); y = sig(r)*(wkv+intra)*sig(g)
__global__ __launch_bounds__(64) void k_out(const unsigned short* __restrict__ wsQ,
                                            const unsigned short* __restrict__ wsI,
                                            const unsigned short* __restrict__ states,
                                            const unsigned short* __restrict__ rgbuf,
                                            unsigned short* __restrict__ ys){
  const int bx = blockIdx.x;
  const int c = bx & (NC-1), bh = bx >> 8;
  const int b = bh >> 3, h = bh & 7;
  const int l = threadIdx.x;
  const int rowbase = b*SEQ + c*CT;

  __shared__ __align__(16) unsigned short q_l [16*72];   // [t][d]
  __shared__ __align__(16) unsigned short st_l[64*72];   // [v][d]

  // stage Q: 16 rows x 64 shorts = 128 x 16B chunks
  #pragma unroll
  for(int i=0;i<2;i++){
    int idx = i*64 + l, t = idx>>3, c8 = idx&7;
    uint4 val = *(const uint4*)&wsQ[(size_t)(rowbase+t)*512 + h*64 + c8*8];
    *(uint4*)&q_l[t*72 + c8*8] = val;
  }
  // stage st (states[bx] is [v][d] contiguous, 4096 shorts)
  #pragma unroll
  for(int i=0;i<8;i++){
    int idx = i*64 + l, v = idx>>3, c8 = idx&7;
    uint4 val = *(const uint4*)&states[(size_t)bx*4096 + (size_t)idx*8];
    *(uint4*)&st_l[v*72 + c8*8] = val;
  }
  __syncthreads();

  f32x4 acc[4];
  #pragma unroll
  for(int vc=0;vc<4;vc++){ f32x4 z = {0.f,0.f,0.f,0.f}; acc[vc] = z; }
  #pragma unroll
  for(int kc=0;kc<2;kc++){
    bf16x8 a = *(const bf16x8*)&q_l[(l&15)*72 + kc*32 + (l>>4)*8];
    #pragma unroll
    for(int vc=0;vc<4;vc++){
      bf16x8 bb = *(const bf16x8*)&st_l[(vc*16 + (l&15))*72 + kc*32 + (l>>4)*8];
      acc[vc] = __builtin_amdgcn_mfma_f32_16x16x32_bf16(a, bb, acc[vc], 0,0,0);
    }
  }
  // epilogue: D col = v = vc*16+(l&15), row t = (l>>4)*4+r
  #pragma unroll
  for(int vc=0;vc<4;vc++)
    #pragma unroll
    for(int r=0;r<4;r++){
      int t = (l>>4)*4 + r;
      int v = vc*16 + (l&15);
      size_t row = (size_t)(rowbase + t);
      float w = acc[vc][r];
      float intra = bf2f(wsI[row*512 + h*64 + v]);
      float rr = bf2f(rgbuf[row*1024 + h*64 + v]);
      float gg = bf2f(rgbuf[row*1024 + 512 + h*64 + v]);
      rr = 1.f/(1.f + expf(-rr));
      gg = 1.f/(1.f + expf(-gg));
      float y = rr*(w + intra)*gg;
      ys[row*512 + h*64 + v] = f2bf(y);
    }
}

// ---------------- launcher ----------------
extern "C" void kernel_launch(void* const* d_in, const int* in_sizes, int n_in,
                              void* d_out, int out_size, void* d_ws, size_t ws_size,
                              hipStream_t stream){
  const float* x          = (const float*)d_in[0];
  const float* W_sel      = (const float*)d_in[1];
  const float* dt_W       = (const float*)d_in[2];
  const float* dt_b       = (const float*)d_in[3];
  const float* Wk         = (const float*)d_in[4];
  const float* Wv         = (const float*)d_in[5];
  const float* Wr         = (const float*)d_in[6];
  const float* Wg         = (const float*)d_in[7];
  const float* Wo         = (const float*)d_in[8];
  const float* base_decay = (const float*)d_in[9];
  const float* time_first = (const float*)d_in[10];
  float* out = (float*)d_out;

  char* wsb = (char*)d_ws;
  unsigned short* Xbf   = (unsigned short*)(wsb + 0);          // 33,554,432
  unsigned short* wsQ   = (unsigned short*)(wsb + 0);          // overlay
  unsigned short* wsI   = (unsigned short*)(wsb + 16777216);   // overlay
  unsigned short* Wcat  = (unsigned short*)(wsb + 33554432);   // 2688 x 1024 bf16
  unsigned short* WoT   = (unsigned short*)(wsb + 39059456);   // 1024 x 512 bf16
  float*          dtbuf = (float*)         (wsb + 40108032);   // 16384 x 512 f32
  unsigned short* ys    = (unsigned short*)(wsb + 40108032);   // overlay
  unsigned short* kvbuf = (unsigned short*)(wsb + 73662464);   // 16384 x 1024 bf16
  unsigned short* rgbuf = (unsigned short*)(wsb + 107216896);  // 16384 x 1024 bf16
  float*          lastb = (float*)         (wsb + 140771328);  // compact [row] f32
  unsigned short* wsU   = (unsigned short*)(wsb + 149159936);  // 8192 x 4096 bf16
  float*          wsA   = (float*)         (wsb + 216268800);  // 2,097,152

  k_prep_x<<<dim3(8192), dim3(256), 0, stream>>>(x, Xbf);
  k_prep_dteff<<<dim3(2048), dim3(256), 0, stream>>>(W_sel, dt_W, Wcat);
  k_transpose<<<dim3(32,16), dim3(256), 0, stream>>>(Wk, Wcat + (size_t)512*1024,  1024, 512);
  k_transpose<<<dim3(32,16), dim3(256), 0, stream>>>(Wv, Wcat + (size_t)1024*1024, 1024, 512);
  k_transpose<<<dim3(32,16), dim3(256), 0, stream>>>(Wr, Wcat + (size_t)1536*1024, 1024, 512);
  k_transpose<<<dim3(32,16), dim3(256), 0, stream>>>(Wg, Wcat + (size_t)2048*1024, 1024, 512);
  k_transpose<<<dim3(16,32), dim3(256), 0, stream>>>(Wo, WoT, 512, 1024);
  k_prep_wbs<<<dim3(4), dim3(256), 0, stream>>>(W_sel, Wcat);
  hipMemsetAsync(Wcat + (size_t)2561*1024, 0, (size_t)127*1024*2, stream);

  k_gemm<0><<<dim3(2688), dim3(256), 0, stream>>>(Xbf, Wcat, 1024, 21, dtbuf, kvbuf, rgbuf, lastb, nullptr);

  k_scan1<<<dim3(8192), dim3(64), 0, stream>>>(dtbuf, kvbuf, lastb, base_decay, dt_b, time_first,
                                               wsQ, wsI, wsU, wsA);
  k_scan2<<<dim3(32,4), dim3(256), 0, stream>>>(wsU, wsA, out + 16777216);
  k_out<<<dim3(8192), dim3(64), 0, stream>>>(wsQ, wsI, wsU, rgbuf, ys);

  k_gemm<1><<<dim3(1024), dim3(256), 0, stream>>>(ys, WoT, 512, 8, nullptr, nullptr, nullptr, nullptr, out);
}